// Round 4
// baseline (820.529 us; speedup 1.0000x reference)
//
#include <hip/hip_runtime.h>
#include <hip/hip_bf16.h>

#define BB 32
#define NN 128
#define EE 16384
#define ROWS_E (BB*EE)     // 524288
#define ROWS_N (BB*NN)     // 4096
#define EPS_BN 1e-5f

// d_out layout (floats): h_out, x_out, m
#define XOUT_OFF (ROWS_N*72)
#define M_OFF    (XOUT_OFF + ROWS_N*4)

// ws layout (floats)
#define ST1_OFF 0            // sum[72], sq[72], mean@144, inv@216, S@288, T@360
#define ST2_OFF 512
#define AGG_OFF 1024
#define CNT_OFF (AGG_OFF + ROWS_N*4)
#define MAGG_OFF (CNT_OFF + ROWS_N)
#define Z2_OFF (MAGG_OFF + ROWS_N*72)     // 316416
#define ZERO_FLOATS Z2_OFF
#define WB_OFF (Z2_OFF + ROWS_N*72)       // 611328 floats
#define Z1BF_OFF 637248                    // floats; z1 bf16 region (optional)
#define Z1BF_NEED ((size_t)(Z1BF_OFF + ROWS_E*72/2) * 4)

// transposed bf16 weight buffer (ushort offsets), layout [n up to 80][K padded]
#define WE1T_OFF 0          // [80][168]
#define WE2T_OFF 13440      // [80][104]
#define WX1T_OFF 21760      // [80][104]
#define WH1T_OFF 30080      // [80][168]
#define WH2T_OFF 43520      // [80][104]
#define WB_TOTAL 51840

typedef __attribute__((ext_vector_type(8))) short short8;
typedef __attribute__((ext_vector_type(4))) float f32x4;

__device__ __forceinline__ float psi_f(float p) {
    return copysignf(log1pf(fabsf(p)), p);
}
__device__ __forceinline__ unsigned short f2bf(float f) {
    union { float f; unsigned u; } v; v.f = f;
    unsigned r = v.u + 0x7fffu + ((v.u >> 16) & 1u);
    return (unsigned short)(r >> 16);
}
__device__ __forceinline__ unsigned pk(float a, float b) {
    union { __hip_bfloat162 h; unsigned u; } cv;
    cv.h = __float22bfloat162_rn(make_float2(a, b));
    return cv.u;
}
__device__ __forceinline__ float bfu2f(unsigned u) {  // low 16 bits = bf16
    union { unsigned u; float f; } v; v.u = u << 16; return v.f;
}

// ---------- weight prep: transpose + bf16, pad n->80, K->168/104 with zeros
__global__ void k_prep(const float* __restrict__ We1, const float* __restrict__ We2,
                       const float* __restrict__ Wx1, const float* __restrict__ Wh1,
                       const float* __restrict__ Wh2, unsigned short* __restrict__ wb)
{
    int idx = blockIdx.x * 256 + threadIdx.x;
    if (idx >= WB_TOTAL) return;
    const float* src; int off = idx, n, k, K;
    if (off < WE2T_OFF)      {                  n = off/168; k = off%168; src = We1; K = 146; }
    else if (off < WX1T_OFF) { off -= WE2T_OFF; n = off/104; k = off%104; src = We2; K = 72; }
    else if (off < WH1T_OFF) { off -= WX1T_OFF; n = off/104; k = off%104; src = Wx1; K = 72; }
    else if (off < WH2T_OFF) { off -= WH1T_OFF; n = off/168; k = off%168; src = Wh1; K = 148; }
    else                     { off -= WH2T_OFF; n = off/104; k = off%104; src = Wh2; K = 72; }
    float v = (n < 72 && k < K) ? src[k * 72 + n] : 0.f;
    wb[idx] = f2bf(v);
}

// ---------- GEMM1 (transposed roles): z1[e][col] ; A=We1^T (M=cols), B=feat rows (N=edges)
// No LDS, no barriers. Each wave: 32 edges, full 72 out-cols.
template<bool BF>
__global__ __launch_bounds__(256) void k_edge_gemm1(
    const float* __restrict__ h, const float* __restrict__ x,
    const int* __restrict__ ei, const int* __restrict__ ej,
    const unsigned short* __restrict__ We1t, void* __restrict__ z1v)
{
    int tid = threadIdx.x;
    int wv = tid >> 6, lane = tid & 63, c = lane & 15, quad = lane >> 4;
    int blk = blockIdx.x;
    int b = blk >> 7;                       // 128 blocks per batch
    size_t ebase = (size_t)blk * 128 + wv * 32;
    const float* hb = h + (size_t)b * 128 * 72;

    int iN[2], jN[2];
    #pragma unroll
    for (int nt = 0; nt < 2; nt++) {
        size_t e = ebase + nt * 16 + c;
        iN[nt] = ei[e]; jN[nt] = ej[e];
    }

    f32x4 acc[2][5] = {};
    #pragma unroll
    for (int kc = 0; kc < 5; kc++) {
        int k0 = kc * 32 + quad * 8;
        int ch = kc * 4 + quad;             // 8-wide k-chunk index, 0..19
        short8 bfr[2];
        #pragma unroll
        for (int nt = 0; nt < 2; nt++) {
            if (ch < 18) {
                const float* p = hb + (ch < 9 ? iN[nt] * 72 + ch * 8
                                              : jN[nt] * 72 + (ch - 9) * 8);
                float4 p0 = *(const float4*)p;
                float4 p1 = *(const float4*)(p + 4);
                short8 t;
                unsigned u0 = pk(p0.x, p0.y), u1 = pk(p0.z, p0.w);
                unsigned u2 = pk(p1.x, p1.y), u3 = pk(p1.z, p1.w);
                t[0] = (short)(u0 & 0xffff); t[1] = (short)(u0 >> 16);
                t[2] = (short)(u1 & 0xffff); t[3] = (short)(u1 >> 16);
                t[4] = (short)(u2 & 0xffff); t[5] = (short)(u2 >> 16);
                t[6] = (short)(u3 & 0xffff); t[7] = (short)(u3 >> 16);
                bfr[nt] = t;
            } else if (ch == 18) {
                float4 xi = *(const float4*)(x + (size_t)(b * 128 + iN[nt]) * 4);
                float4 xj = *(const float4*)(x + (size_t)(b * 128 + jN[nt]) * 4);
                float d0 = xi.x-xj.x, d1 = xi.y-xj.y, d2 = xi.z-xj.z, d3 = xi.w-xj.w;
                float nrm = d0*d0 - d1*d1 - d2*d2 - d3*d3;
                float dot = xi.x*xj.x - xi.y*xj.y - xi.z*xj.z - xi.w*xj.w;
                unsigned u = pk(psi_f(nrm), psi_f(dot));
                short8 t = {0,0,0,0,0,0,0,0};
                t[0] = (short)(u & 0xffff); t[1] = (short)(u >> 16);
                bfr[nt] = t;
            } else {
                short8 t = {0,0,0,0,0,0,0,0};
                bfr[nt] = t;
            }
        }
        #pragma unroll
        for (int mt = 0; mt < 5; mt++) {
            short8 w = *(const short8*)(We1t + (mt * 16 + c) * 168 + k0);
            acc[0][mt] = __builtin_amdgcn_mfma_f32_16x16x32_bf16(w, bfr[0], acc[0][mt], 0, 0, 0);
            acc[1][mt] = __builtin_amdgcn_mfma_f32_16x16x32_bf16(w, bfr[1], acc[1][mt], 0, 0, 0);
        }
    }
    #pragma unroll
    for (int nt = 0; nt < 2; nt++) {
        size_t e = ebase + nt * 16 + c;
        #pragma unroll
        for (int mt = 0; mt < 5; mt++) {
            int col0 = mt * 16 + quad * 4;
            if (col0 < 72) {
                if (BF) {
                    unsigned short* z1bf = (unsigned short*)z1v;
                    *(uint2*)(z1bf + e * 72 + col0) =
                        make_uint2(pk(acc[nt][mt][0], acc[nt][mt][1]),
                                   pk(acc[nt][mt][2], acc[nt][mt][3]));
                } else {
                    float* z1f = (float*)z1v;
                    *(float4*)(z1f + e * 72 + col0) =
                        make_float4(acc[nt][mt][0], acc[nt][mt][1],
                                    acc[nt][mt][2], acc[nt][mt][3]);
                }
            }
        }
    }
}

// ---------- per-channel sum/sumsq, fp32 rows
__global__ void k_stats(const float* __restrict__ z, int rows, float* __restrict__ st)
{
    __shared__ float ssum[4][72];
    __shared__ float ssq[4][72];
    int c = threadIdx.x, ty = threadIdx.y;
    float s = 0.f, q = 0.f;
    for (int r = blockIdx.x * 4 + ty; r < rows; r += gridDim.x * 4) {
        float v = z[(size_t)r * 72 + c];
        s += v; q += v * v;
    }
    ssum[ty][c] = s; ssq[ty][c] = q;
    __syncthreads();
    if (ty == 0) {
        s = ssum[0][c] + ssum[1][c] + ssum[2][c] + ssum[3][c];
        q = ssq[0][c] + ssq[1][c] + ssq[2][c] + ssq[3][c];
        atomicAdd(&st[c], s);
        atomicAdd(&st[72 + c], q);
    }
}

// ---------- per-channel sum/sumsq, bf16 rows (z1u = 36 uints per row)
__global__ void k_stats_bf(const unsigned* __restrict__ z1u, float* __restrict__ st)
{
    __shared__ float ssum[7][72];
    __shared__ float ssq[7][72];
    int p = threadIdx.x;      // 0..35 (col pair)
    int ty = threadIdx.y;     // 0..6
    float s0 = 0.f, s1 = 0.f, q0 = 0.f, q1 = 0.f;
    for (int r = blockIdx.x * 7 + ty; r < ROWS_E; r += gridDim.x * 7) {
        unsigned v = z1u[(size_t)r * 36 + p];
        float a = bfu2f(v & 0xffffu);
        float bb = bfu2f(v >> 16);
        s0 += a; q0 += a * a; s1 += bb; q1 += bb * bb;
    }
    ssum[ty][2*p] = s0; ssum[ty][2*p+1] = s1;
    ssq[ty][2*p] = q0;  ssq[ty][2*p+1] = q1;
    __syncthreads();
    if (ty == 0) {
        #pragma unroll
        for (int hh = 0; hh < 2; hh++) {
            int col = 2*p + hh;
            float s = 0.f, q = 0.f;
            #pragma unroll
            for (int t = 0; t < 7; t++) { s += ssum[t][col]; q += ssq[t][col]; }
            atomicAdd(&st[col], s);
            atomicAdd(&st[72 + col], q);
        }
    }
}

// ---------- finalize: mean/inv (for node path) + fused BN scale/shift S,T
__global__ void k_finalize(float* __restrict__ st, float inv_rows,
                           const float* __restrict__ g, const float* __restrict__ b)
{
    int c = threadIdx.x;
    if (c < 72) {
        float mean = st[c] * inv_rows;
        float var  = st[72 + c] * inv_rows - mean * mean;
        float rst  = rsqrtf(var + EPS_BN);
        st[144 + c] = mean;
        st[216 + c] = rst;
        float S = rst * g[c];
        st[288 + c] = S;
        st[360 + c] = b[c] - mean * S;
    }
}

// ---------- edge main (transposed): BN(z1)->GEMM2->gate->m ; GEMM3->g2->agg/cnt
template<bool BF>
__global__ __launch_bounds__(256) void k_edge_main(
    const void* __restrict__ z1v, const float* __restrict__ x,
    const int* __restrict__ ei, const int* __restrict__ ej,
    const float* __restrict__ st1, const float* __restrict__ be2,
    const float* __restrict__ Wm, const float* __restrict__ bm,
    const float* __restrict__ bx1, const float* __restrict__ Wx2,
    const unsigned short* __restrict__ We2t, const unsigned short* __restrict__ Wx1t,
    float* __restrict__ m, float* __restrict__ agg, float* __restrict__ cnt)
{
    __shared__ unsigned short mtile[128 * 72];
    int tid = threadIdx.x;
    int wv = tid >> 6, lane = tid & 63, c = lane & 15, quad = lane >> 4;
    int blk = blockIdx.x;
    int b = blk >> 7;
    size_t ebase = (size_t)blk * 128 + wv * 32;
    const float* Sp = st1 + 288;
    const float* Tp = st1 + 360;

    // B-fragments: a = relu(z1*S + T), packed bf16
    short8 zb[2][3];
    #pragma unroll
    for (int kc = 0; kc < 3; kc++) {
        int k0 = kc * 32 + quad * 8;
        if (k0 < 72) {
            float4 Sa = *(const float4*)(Sp + k0), Sb4 = *(const float4*)(Sp + k0 + 4);
            float4 Ta = *(const float4*)(Tp + k0), Tb4 = *(const float4*)(Tp + k0 + 4);
            #pragma unroll
            for (int nt = 0; nt < 2; nt++) {
                size_t e = ebase + nt * 16 + c;
                float v0,v1,v2,v3,v4,v5,v6,v7;
                if (BF) {
                    const unsigned* z1u = (const unsigned*)z1v;
                    uint4 u = *(const uint4*)(z1u + e * 36 + (k0 >> 1));
                    v0 = bfu2f(u.x & 0xffffu); v1 = bfu2f(u.x >> 16);
                    v2 = bfu2f(u.y & 0xffffu); v3 = bfu2f(u.y >> 16);
                    v4 = bfu2f(u.z & 0xffffu); v5 = bfu2f(u.z >> 16);
                    v6 = bfu2f(u.w & 0xffffu); v7 = bfu2f(u.w >> 16);
                } else {
                    const float* z1f = (const float*)z1v;
                    float4 p0 = *(const float4*)(z1f + e * 72 + k0);
                    float4 p1 = *(const float4*)(z1f + e * 72 + k0 + 4);
                    v0 = p0.x; v1 = p0.y; v2 = p0.z; v3 = p0.w;
                    v4 = p1.x; v5 = p1.y; v6 = p1.z; v7 = p1.w;
                }
                float a0 = fmaxf(v0*Sa.x + Ta.x, 0.f), a1 = fmaxf(v1*Sa.y + Ta.y, 0.f);
                float a2 = fmaxf(v2*Sa.z + Ta.z, 0.f), a3 = fmaxf(v3*Sa.w + Ta.w, 0.f);
                float a4 = fmaxf(v4*Sb4.x + Tb4.x, 0.f), a5 = fmaxf(v5*Sb4.y + Tb4.y, 0.f);
                float a6 = fmaxf(v6*Sb4.z + Tb4.z, 0.f), a7 = fmaxf(v7*Sb4.w + Tb4.w, 0.f);
                unsigned u0 = pk(a0,a1), u1 = pk(a2,a3), u2 = pk(a4,a5), u3 = pk(a6,a7);
                short8 t;
                t[0]=(short)(u0&0xffff); t[1]=(short)(u0>>16);
                t[2]=(short)(u1&0xffff); t[3]=(short)(u1>>16);
                t[4]=(short)(u2&0xffff); t[5]=(short)(u2>>16);
                t[6]=(short)(u3&0xffff); t[7]=(short)(u3>>16);
                zb[nt][kc] = t;
            }
        } else {
            short8 t = {0,0,0,0,0,0,0,0};
            zb[0][kc] = t; zb[1][kc] = t;
        }
    }

    // GEMM2: t = relu(z_bn @ We2 + be2)
    f32x4 acc2[2][5] = {};
    #pragma unroll
    for (int kc = 0; kc < 3; kc++) {
        int k0 = kc * 32 + quad * 8;
        #pragma unroll
        for (int mt = 0; mt < 5; mt++) {
            short8 w = *(const short8*)(We2t + (mt * 16 + c) * 104 + k0);
            acc2[0][mt] = __builtin_amdgcn_mfma_f32_16x16x32_bf16(w, zb[0][kc], acc2[0][mt], 0, 0, 0);
            acc2[1][mt] = __builtin_amdgcn_mfma_f32_16x16x32_bf16(w, zb[1][kc], acc2[1][mt], 0, 0, 0);
        }
    }
    float part[2] = {0.f, 0.f};
    #pragma unroll
    for (int mt = 0; mt < 5; mt++) {
        int col0 = mt * 16 + quad * 4;
        float4 be = make_float4(0,0,0,0), wm = make_float4(0,0,0,0);
        if (col0 < 72) { be = *(const float4*)(be2 + col0); wm = *(const float4*)(Wm + col0); }
        #pragma unroll
        for (int nt = 0; nt < 2; nt++) {
            float t0 = fmaxf(acc2[nt][mt][0] + be.x, 0.f);
            float t1 = fmaxf(acc2[nt][mt][1] + be.y, 0.f);
            float t2 = fmaxf(acc2[nt][mt][2] + be.z, 0.f);
            float t3 = fmaxf(acc2[nt][mt][3] + be.w, 0.f);
            acc2[nt][mt][0] = t0; acc2[nt][mt][1] = t1;
            acc2[nt][mt][2] = t2; acc2[nt][mt][3] = t3;
            part[nt] += t0*wm.x + t1*wm.y + t2*wm.z + t3*wm.w;
        }
    }
    float bm0 = bm[0];
    float gate[2];
    #pragma unroll
    for (int nt = 0; nt < 2; nt++) {
        float s = part[nt];
        s += __shfl_xor(s, 16);
        s += __shfl_xor(s, 32);
        gate[nt] = 1.f / (1.f + expf(-(s + bm0)));
    }
    // m = t*gate: packed global fp32 store + LDS bf16 (wave-local rows)
    #pragma unroll
    for (int nt = 0; nt < 2; nt++) {
        size_t e = ebase + nt * 16 + c;
        int el = wv * 32 + nt * 16 + c;
        #pragma unroll
        for (int mt = 0; mt < 5; mt++) {
            int col0 = mt * 16 + quad * 4;
            if (col0 < 72) {
                float m0 = acc2[nt][mt][0] * gate[nt];
                float m1 = acc2[nt][mt][1] * gate[nt];
                float m2 = acc2[nt][mt][2] * gate[nt];
                float m3 = acc2[nt][mt][3] * gate[nt];
                *(float4*)(m + e * 72 + col0) = make_float4(m0, m1, m2, m3);
                *(uint2*)(&mtile[el * 72 + col0]) = make_uint2(pk(m0, m1), pk(m2, m3));
            }
        }
    }
    // GEMM3: u = m @ Wx1 ; g2 = relu(u+bx1) . Wx2  (wave-local LDS rows, no barrier)
    f32x4 acc3[2][5] = {};
    #pragma unroll
    for (int kc = 0; kc < 3; kc++) {
        int k0 = kc * 32 + quad * 8;
        short8 mb[2];
        #pragma unroll
        for (int nt = 0; nt < 2; nt++) {
            if (k0 < 72) mb[nt] = *(const short8*)(&mtile[(wv*32 + nt*16 + c) * 72 + k0]);
            else { short8 t = {0,0,0,0,0,0,0,0}; mb[nt] = t; }
        }
        #pragma unroll
        for (int mt = 0; mt < 5; mt++) {
            short8 w = *(const short8*)(Wx1t + (mt * 16 + c) * 104 + k0);
            acc3[0][mt] = __builtin_amdgcn_mfma_f32_16x16x32_bf16(w, mb[0], acc3[0][mt], 0, 0, 0);
            acc3[1][mt] = __builtin_amdgcn_mfma_f32_16x16x32_bf16(w, mb[1], acc3[1][mt], 0, 0, 0);
        }
    }
    float part3[2] = {0.f, 0.f};
    #pragma unroll
    for (int mt = 0; mt < 5; mt++) {
        int col0 = mt * 16 + quad * 4;
        float4 bx = make_float4(0,0,0,0), wx = make_float4(0,0,0,0);
        if (col0 < 72) { bx = *(const float4*)(bx1 + col0); wx = *(const float4*)(Wx2 + col0); }
        #pragma unroll
        for (int nt = 0; nt < 2; nt++) {
            part3[nt] += fmaxf(acc3[nt][mt][0] + bx.x, 0.f) * wx.x
                       + fmaxf(acc3[nt][mt][1] + bx.y, 0.f) * wx.y
                       + fmaxf(acc3[nt][mt][2] + bx.z, 0.f) * wx.z
                       + fmaxf(acc3[nt][mt][3] + bx.w, 0.f) * wx.w;
        }
    }
    float g2v[2];
    #pragma unroll
    for (int nt = 0; nt < 2; nt++) {
        float s = part3[nt];
        s += __shfl_xor(s, 16);
        s += __shfl_xor(s, 32);
        g2v[nt] = s;
    }
    // x-update scatter: quads 0,1 handle nt=0,1
    if (quad < 2) {
        size_t e = ebase + quad * 16 + c;
        float g2 = quad ? g2v[1] : g2v[0];
        int i2 = ei[e], j2 = ej[e];
        float4 xi = *(const float4*)(x + (size_t)(b * 128 + i2) * 4);
        float4 xj = *(const float4*)(x + (size_t)(b * 128 + j2) * 4);
        float t0 = fminf(fmaxf((xi.x - xj.x) * g2, -100.f), 100.f);
        float t1 = fminf(fmaxf((xi.y - xj.y) * g2, -100.f), 100.f);
        float t2 = fminf(fmaxf((xi.z - xj.z) * g2, -100.f), 100.f);
        float t3 = fminf(fmaxf((xi.w - xj.w) * g2, -100.f), 100.f);
        float* ap = agg + (size_t)(b * 128 + i2) * 4;
        atomicAdd(ap + 0, t0); atomicAdd(ap + 1, t1);
        atomicAdd(ap + 2, t2); atomicAdd(ap + 3, t3);
        atomicAdd(cnt + (size_t)(b * 128 + i2), 1.f);
    }
}

// ---------- magg: segment-sum of m over edges, LDS-staged
__global__ __launch_bounds__(256) void k_magg(
    const float* __restrict__ m, const int* __restrict__ ei, float* __restrict__ magg)
{
    __shared__ float accum[128 * 72];
    int tid = threadIdx.x;
    for (int q = tid; q < 9216; q += 256) accum[q] = 0.f;
    __syncthreads();
    int b = blockIdx.x >> 3, chunk = blockIdx.x & 7;
    int wv = tid >> 6, lane = tid & 63;
    int ebase = b * 16384 + chunk * 2048;
    for (int e = wv; e < 2048; e += 4) {
        int erow = ebase + e;
        int node = ei[erow];
        const float* mr = m + (size_t)erow * 72;
        atomicAdd(&accum[node * 72 + lane], mr[lane]);
        if (lane < 8) atomicAdd(&accum[node * 72 + 64 + lane], mr[64 + lane]);
    }
    __syncthreads();
    float* mg = magg + (size_t)b * 9216;
    for (int q = tid; q < 9216; q += 256) atomicAdd(&mg[q], accum[q]);
}

// ---------- node GEMM1: z2 = [h, magg, node_attr] @ Wh1 + bh1 (round-3 style)
__global__ __launch_bounds__(256) void k_node_gemm1(
    const float* __restrict__ h, const float* __restrict__ node_attr,
    const float* __restrict__ magg, const unsigned short* __restrict__ Wh1t,
    const float* __restrict__ bh1, float* __restrict__ z2)
{
    __shared__ unsigned short At[128 * 168];
    __shared__ unsigned short Wt[80 * 168];
    int tid = threadIdx.x;
    {
        const uint4* s = (const uint4*)Wh1t; uint4* d = (uint4*)Wt;
        for (int q = tid; q < 1680; q += 256) d[q] = s[q];
    }
    int rl = tid >> 1, half = tid & 1;
    size_t row = (size_t)blockIdx.x * 128 + rl;
    const float4* sp = (const float4*)((half ? magg : h) + row * 72);
    uint2* arow = (uint2*)(&At[rl * 168 + half * 72]);
    #pragma unroll
    for (int q = 0; q < 18; q++) {
        float4 v = sp[q];
        arow[q] = make_uint2(pk(v.x, v.y), pk(v.z, v.w));
    }
    if (half) {
        float4 na = *(const float4*)(node_attr + row * 4);
        *(unsigned*)(&At[rl * 168 + 144]) = pk(na.x, na.y);
        *(unsigned*)(&At[rl * 168 + 146]) = pk(na.z, na.w);
        unsigned* tailp = (unsigned*)(&At[rl * 168 + 148]);
        #pragma unroll
        for (int q = 0; q < 10; q++) tailp[q] = 0u;
    }
    __syncthreads();

    int wv = tid >> 6, lane = tid & 63, c = lane & 15, quad = lane >> 4;
    f32x4 acc[2][5] = {};
    for (int kc = 0; kc < 5; kc++) {
        int k0 = kc * 32 + quad * 8;
        short8 a0 = *(const short8*)(&At[(wv * 32 + c) * 168 + k0]);
        short8 a1 = *(const short8*)(&At[(wv * 32 + 16 + c) * 168 + k0]);
        #pragma unroll
        for (int ct = 0; ct < 5; ct++) {
            short8 bfw = *(const short8*)(&Wt[(ct * 16 + c) * 168 + k0]);
            acc[0][ct] = __builtin_amdgcn_mfma_f32_16x16x32_bf16(a0, bfw, acc[0][ct], 0, 0, 0);
            acc[1][ct] = __builtin_amdgcn_mfma_f32_16x16x32_bf16(a1, bfw, acc[1][ct], 0, 0, 0);
        }
    }
    size_t rbase = (size_t)blockIdx.x * 128 + wv * 32 + quad * 4;
    #pragma unroll
    for (int rt = 0; rt < 2; rt++)
        #pragma unroll
        for (int ct = 0; ct < 5; ct++) {
            int col = ct * 16 + c;
            if (col < 72) {
                float bias = bh1[col];
                float* op = z2 + (rbase + rt * 16) * 72 + col;
                #pragma unroll
                for (int r = 0; r < 4; r++) op[(size_t)r * 72] = acc[rt][ct][r] + bias;
            }
        }
}

// ---------- node final: BN2+ReLU -> MFMA @Wh2 + bh2 + h ; x_out
__global__ __launch_bounds__(256) void k_node_final(
    const float* __restrict__ h, const float* __restrict__ x,
    const float* __restrict__ z2, const float* __restrict__ st2,
    const float* __restrict__ gh, const float* __restrict__ bh,
    const unsigned short* __restrict__ Wh2t, const float* __restrict__ bh2,
    const float* __restrict__ agg, const float* __restrict__ cnt,
    float* __restrict__ hout, float* __restrict__ xout)
{
    __shared__ unsigned short Zt[128 * 104];
    __shared__ unsigned short Wt[80 * 104];
    int tid = threadIdx.x;
    {
        const uint4* s = (const uint4*)Wh2t; uint4* d = (uint4*)Wt;
        for (int q = tid; q < 1040; q += 256) d[q] = s[q];
    }
    int rl = tid >> 1, half = tid & 1;
    size_t row = (size_t)blockIdx.x * 128 + rl;
    const float* mean = st2 + 144;
    const float* inv  = st2 + 216;
    const float4* zp = (const float4*)(z2 + row * 72) + half * 9;
    uint2* arow = (uint2*)(&Zt[rl * 104 + half * 36]);
    #pragma unroll
    for (int q = 0; q < 9; q++) {
        int k = half * 36 + q * 4;
        float4 v = zp[q];
        float a0 = fmaxf((v.x - mean[k  ]) * inv[k  ] * gh[k  ] + bh[k  ], 0.f);
        float a1 = fmaxf((v.y - mean[k+1]) * inv[k+1] * gh[k+1] + bh[k+1], 0.f);
        float a2 = fmaxf((v.z - mean[k+2]) * inv[k+2] * gh[k+2] + bh[k+2], 0.f);
        float a3 = fmaxf((v.w - mean[k+3]) * inv[k+3] * gh[k+3] + bh[k+3], 0.f);
        arow[q] = make_uint2(pk(a0, a1), pk(a2, a3));
    }
    uint2* prow = (uint2*)(&Zt[rl * 104]);
    #pragma unroll
    for (int q = 0; q < 4; q++) prow[18 + half * 4 + q] = make_uint2(0u, 0u);
    __syncthreads();

    int wv = tid >> 6, lane = tid & 63, c = lane & 15, quad = lane >> 4;
    f32x4 acc[2][5] = {};
    for (int kc = 0; kc < 3; kc++) {
        int k0 = kc * 32 + quad * 8;
        short8 a0 = *(const short8*)(&Zt[(wv * 32 + c) * 104 + k0]);
        short8 a1 = *(const short8*)(&Zt[(wv * 32 + 16 + c) * 104 + k0]);
        #pragma unroll
        for (int ct = 0; ct < 5; ct++) {
            short8 bfw = *(const short8*)(&Wt[(ct * 16 + c) * 104 + k0]);
            acc[0][ct] = __builtin_amdgcn_mfma_f32_16x16x32_bf16(a0, bfw, acc[0][ct], 0, 0, 0);
            acc[1][ct] = __builtin_amdgcn_mfma_f32_16x16x32_bf16(a1, bfw, acc[1][ct], 0, 0, 0);
        }
    }
    size_t rbase = (size_t)blockIdx.x * 128 + wv * 32 + quad * 4;
    #pragma unroll
    for (int rt = 0; rt < 2; rt++)
        #pragma unroll
        for (int ct = 0; ct < 5; ct++) {
            int col = ct * 16 + c;
            if (col < 72) {
                float bias = bh2[col];
                #pragma unroll
                for (int r = 0; r < 4; r++) {
                    size_t gr = (rbase + rt * 16 + r);
                    hout[gr * 72 + col] = h[gr * 72 + col] + acc[rt][ct][r] + bias;
                }
            }
        }
    if (tid < 128) {
        size_t nrow = (size_t)blockIdx.x * 128 + tid;
        float cn = fmaxf(cnt[nrow], 1.f);
        float4 ag = *(const float4*)(agg + nrow * 4);
        float4 xv = *(const float4*)(x + nrow * 4);
        ((float4*)xout)[nrow] = make_float4(xv.x + ag.x / cn, xv.y + ag.y / cn,
                                            xv.z + ag.z / cn, xv.w + ag.w / cn);
    }
}

extern "C" void kernel_launch(void* const* d_in, const int* in_sizes, int n_in,
                              void* d_out, int out_size, void* d_ws, size_t ws_size,
                              hipStream_t stream)
{
    const float* h   = (const float*)d_in[0];
    const float* x   = (const float*)d_in[1];
    const int*   ei  = (const int*)d_in[2];
    const int*   ej  = (const int*)d_in[3];
    const float* na  = (const float*)d_in[4];
    const float* We1 = (const float*)d_in[5];
    const float* g1  = (const float*)d_in[6];
    const float* b1  = (const float*)d_in[7];
    const float* We2 = (const float*)d_in[8];
    const float* be2 = (const float*)d_in[9];
    const float* Wm  = (const float*)d_in[10];
    const float* bm  = (const float*)d_in[11];
    const float* Wx1 = (const float*)d_in[12];
    const float* bx1 = (const float*)d_in[13];
    const float* Wx2 = (const float*)d_in[14];
    const float* Wh1 = (const float*)d_in[15];
    const float* bh1 = (const float*)d_in[16];
    const float* gh  = (const float*)d_in[17];
    const float* bhp = (const float*)d_in[18];
    const float* Wh2 = (const float*)d_in[19];
    const float* bh2 = (const float*)d_in[20];

    float* out  = (float*)d_out;
    float* hout = out;
    float* xout = out + XOUT_OFF;
    float* m    = out + M_OFF;
    float* ws   = (float*)d_ws;
    float* st1  = ws + ST1_OFF;
    float* st2  = ws + ST2_OFF;
    float* agg  = ws + AGG_OFF;
    float* cnt  = ws + CNT_OFF;
    float* magg = ws + MAGG_OFF;
    float* z2   = ws + Z2_OFF;
    unsigned short* wb = (unsigned short*)(ws + WB_OFF);
    unsigned short* z1bf = (unsigned short*)(ws + Z1BF_OFF);

    // bf16 z1 path only if ws is big enough; decision is launch-invariant.
    bool bf = ws_size >= Z1BF_NEED;
    void* z1v = bf ? (void*)z1bf : (void*)m;   // fp32 fallback: z1 lives in m region

    hipMemsetAsync(d_ws, 0, (size_t)ZERO_FLOATS * sizeof(float), stream);
    k_prep<<<(WB_TOTAL + 255) / 256, 256, 0, stream>>>(We1, We2, Wx1, Wh1, Wh2, wb);
    if (bf) {
        k_edge_gemm1<true><<<ROWS_E / 128, 256, 0, stream>>>(h, x, ei, ej, wb + WE1T_OFF, z1v);
        k_stats_bf<<<2048, dim3(36, 7), 0, stream>>>((const unsigned*)z1bf, st1);
    } else {
        k_edge_gemm1<false><<<ROWS_E / 128, 256, 0, stream>>>(h, x, ei, ej, wb + WE1T_OFF, z1v);
        k_stats<<<2048, dim3(72, 4), 0, stream>>>((const float*)z1v, ROWS_E, st1);
    }
    k_finalize<<<1, 128, 0, stream>>>(st1, 1.0f / (float)ROWS_E, g1, b1);
    if (bf) {
        k_edge_main<true><<<ROWS_E / 128, 256, 0, stream>>>(z1v, x, ei, ej, st1, be2, Wm, bm,
                                                            bx1, Wx2, wb + WE2T_OFF, wb + WX1T_OFF,
                                                            m, agg, cnt);
    } else {
        k_edge_main<false><<<ROWS_E / 128, 256, 0, stream>>>(z1v, x, ei, ej, st1, be2, Wm, bm,
                                                             bx1, Wx2, wb + WE2T_OFF, wb + WX1T_OFF,
                                                             m, agg, cnt);
    }
    k_magg<<<256, 256, 0, stream>>>(m, ei, magg);
    k_node_gemm1<<<ROWS_N / 128, 256, 0, stream>>>(h, na, magg, wb + WH1T_OFF, bh1, z2);
    k_stats<<<16, dim3(72, 4), 0, stream>>>(z2, ROWS_N, st2);
    k_finalize<<<1, 128, 0, stream>>>(st2, 1.0f / (float)ROWS_N, gh, bhp);
    k_node_final<<<ROWS_N / 128, 256, 0, stream>>>(h, x, z2, st2, gh, bhp,
                                                   wb + WH2T_OFF, bh2, agg, cnt, hout, xout);
}